// Round 8
// baseline (688.777 us; speedup 1.0000x reference)
//
#include <hip/hip_runtime.h>

typedef unsigned short ushort_t;
typedef __attribute__((ext_vector_type(8))) short short8;
typedef __attribute__((ext_vector_type(4))) float f32x4;

// ---------- helpers ----------

__device__ __forceinline__ ushort_t f2bf(float f) {
    unsigned u = __builtin_bit_cast(unsigned, f);
    u += 0x7fffu + ((u >> 16) & 1u);   // round-to-nearest-even
    return (ushort_t)(u >> 16);
}

__device__ __forceinline__ float bf2f(ushort_t h) {
    unsigned u = ((unsigned)h) << 16;
    return __builtin_bit_cast(float, u);
}

__device__ __forceinline__ float tanh_fast(float x) {
    float e = __expf(2.0f * x);
    float r = __builtin_amdgcn_rcpf(e + 1.0f);
    return __builtin_fmaf(-2.0f, r, 1.0f);
}

__device__ __forceinline__ void gld16(const ushort_t* g, ushort_t* lds) {
    __builtin_amdgcn_global_load_lds(
        (const __attribute__((address_space(1))) unsigned int*)g,
        (__attribute__((address_space(3))) unsigned int*)lds, 16, 0, 0);
}

// ---------- K_front: enc/Wenc fp32->bf16 + zero scores (blocks 0..8191)
//                     dproj = dh@Wdec^T + bdec + benc      (blocks 8192..16383)

__global__ __launch_bounds__(256) void k_front(const float* __restrict__ enc,
                                               const float* __restrict__ Wenc,
                                               const float* __restrict__ dh,
                                               const float* __restrict__ Wd,
                                               const float* __restrict__ bd,
                                               const float* __restrict__ be,
                                               ushort_t* __restrict__ encB,
                                               ushort_t* __restrict__ wencB,
                                               float* __restrict__ dproj,
                                               float4* __restrict__ scores4) {
    const int bx = blockIdx.x;
    const int t = threadIdx.x;
    if (bx < 8192) {
        int i = bx * 256 + t;
        for (; i < 17055744; i += 2097152) {
            if (i < 16777216) {                       // enc: 16.7M float4
                float4 v = ((const float4*)enc)[i];
                ushort4 o;
                o.x = f2bf(v.x); o.y = f2bf(v.y); o.z = f2bf(v.z); o.w = f2bf(v.w);
                ((ushort4*)encB)[i] = o;
            } else if (i < 17039360) {                // Wenc: 262144 float4
                int j = i - 16777216;
                float4 v = ((const float4*)Wenc)[j];
                ushort4 o;
                o.x = f2bf(v.x); o.y = f2bf(v.y); o.z = f2bf(v.z); o.w = f2bf(v.w);
                ((ushort4*)wencB)[j] = o;
            } else {                                  // scores zeros
                scores4[i - 17039360] = (float4){0.f, 0.f, 0.f, 0.f};
            }
        }
    } else {
        int wid = (bx - 8192) * 4 + (t >> 6);
        int lane = t & 63;
        int a = wid & 1023, b = wid >> 10;
        const float4* x = (const float4*)(dh + (size_t)b * 1024);
        const float4* wrow = (const float4*)(Wd + (size_t)a * 1024);
        float s = 0.f;
#pragma unroll
        for (int it = 0; it < 4; ++it) {
            int c = it * 64 + lane;
            float4 xv = x[c], wv = wrow[c];
            s += xv.x * wv.x + xv.y * wv.y + xv.z * wv.z + xv.w * wv.w;
        }
#pragma unroll
        for (int o = 1; o < 64; o <<= 1) s += __shfl_xor(s, o, 64);
        if (lane == 0) dproj[b * 1024 + a] = s + bd[a] + be[a];
    }
}

// ---------- K2: fused GEMM + tanh + W_v reduction -> scores ----------
// Round-7 structure (simple 2-barrier loop, global_load_lds, XOR swizzle,
// 128x128 tile, 4 waves 2x2, wave tile 64x64, BK=64, 32 KB LDS).
// ONE change vs round 7: residency 3 -> 5 blocks/CU (launch_bounds(256,5)).
// Staging is 97% L2-served (~360cy/tile) vs 640cy compute; the per-tile
// vmcnt(0)+barrier drain is hidden by OTHER resident blocks' compute, so
// max out residency (VGPR 72 <= 102 cap, 5 x 32KB = 160KB LDS pool exactly).

__global__ __launch_bounds__(256, 5) void k_gemm_scores(const ushort_t* __restrict__ A,
                                                        const ushort_t* __restrict__ Bm,
                                                        const float* __restrict__ dproj,
                                                        const float* __restrict__ Wv,
                                                        float* __restrict__ scores) {
    __shared__ __align__(16) ushort_t At[128 * 64];  // 16 KB
    __shared__ __align__(16) ushort_t Bt[128 * 64];  // 16 KB

    const int tid = threadIdx.x;
    const int lane = tid & 63;
    const int w = tid >> 6;            // wave 0..3
    const int wm = w >> 1, wn = w & 1; // waves: 2 (M) x 2 (N); wave tile 64x64

    // bijective XCD map (4096 % 8 == 0): the 8 N-sharers of an A-panel are
    // consecutive work-units on one XCD -> A-panel L2 locality.
    const int blk = blockIdx.x;        // 0..4095
    const int xcd = blk & 7;
    const int idx = blk >> 3;          // 0..511
    const int blkN = idx & 7;          // 0..7
    const int blkM = xcd + ((idx >> 3) << 3);  // 0..511
    const long long arow0 = (long long)blkM * 128;
    const int brow0 = blkN * 128;

    const int sr = lane >> 3;          // row within 8-row staging group
    const int sgrp = lane & 7;         // 16B slot within row
    const int c8s = sgrp ^ sr;         // XOR-swizzled source column-group

    const int q = lane >> 4;           // quad
    const int ml = lane & 15;

    // wave w stages rows [w*32, w*32+32) of each 128-row panel (4 passes of 8)
    const ushort_t* ga = A + (arow0 + w * 32 + sr) * 1024 + c8s * 8;
    const ushort_t* gb = Bm + (long long)(brow0 + w * 32 + sr) * 1024 + c8s * 8;

    f32x4 acc[4][4];
#pragma unroll
    for (int i = 0; i < 4; ++i)
#pragma unroll
        for (int jj = 0; jj < 4; ++jj) acc[i][jj] = (f32x4){0.f, 0.f, 0.f, 0.f};

    for (int k0 = 0; k0 < 1024; k0 += 64) {
        __syncthreads();   // previous compute done before overwriting LDS
#pragma unroll
        for (int j = 0; j < 4; ++j)                   // A: 32 rows per wave
            gld16(ga + j * 8192, &At[(w * 4 + j) * 512]);
#pragma unroll
        for (int j = 0; j < 4; ++j)                   // B: 32 rows per wave
            gld16(gb + j * 8192, &Bt[(w * 4 + j) * 512]);
        ga += 64; gb += 64;
        __builtin_amdgcn_s_waitcnt(0);  // drain vmcnt before barrier
        __syncthreads();

#pragma unroll
        for (int kk = 0; kk < 2; ++kk) {  // two k-steps of 32
            const int kb = kk * 4;
            const int slot = (kb + q) ^ (ml & 7);     // same for A and B frags
            short8 af[4], bfr[4];
#pragma unroll
            for (int i = 0; i < 4; ++i) {
                int row = wm * 64 + i * 16 + ml;
                af[i] = *(const short8*)&At[row * 64 + slot * 8];
            }
#pragma unroll
            for (int jj = 0; jj < 4; ++jj) {
                int col = wn * 64 + jj * 16 + ml;
                bfr[jj] = *(const short8*)&Bt[col * 64 + slot * 8];
            }
#pragma unroll
            for (int i = 0; i < 4; ++i)
#pragma unroll
                for (int jj = 0; jj < 4; ++jj)
                    acc[i][jj] = __builtin_amdgcn_mfma_f32_16x16x32_bf16(
                        af[i], bfr[jj], acc[i][jj], 0, 0, 0);
        }
    }

    // epilogue: scores[m] += sum_a Wv[a]*tanh(acc + dproj[b,a]) over 128 cols
    const int bb = blkM >> 4;  // 16 M-blocks (128 rows) per batch (2048 rows)
    float dp[4], wv[4];
#pragma unroll
    for (int jj = 0; jj < 4; ++jj) {
        int a = blkN * 128 + wn * 64 + jj * 16 + ml;
        dp[jj] = dproj[bb * 1024 + a];
        wv[jj] = Wv[a];
    }
#pragma unroll
    for (int i = 0; i < 4; ++i) {
        float rs[4] = {0.f, 0.f, 0.f, 0.f};
#pragma unroll
        for (int jj = 0; jj < 4; ++jj) {
            f32x4 v = acc[i][jj];
            rs[0] += wv[jj] * tanh_fast(v.x + dp[jj]);
            rs[1] += wv[jj] * tanh_fast(v.y + dp[jj]);
            rs[2] += wv[jj] * tanh_fast(v.z + dp[jj]);
            rs[3] += wv[jj] * tanh_fast(v.w + dp[jj]);
        }
#pragma unroll
        for (int r = 0; r < 4; ++r)
#pragma unroll
            for (int o = 1; o < 16; o <<= 1) rs[r] += __shfl_xor(rs[r], o, 64);
        if (ml == 0) {
            long long m0 = arow0 + wm * 64 + i * 16 + q * 4;
            atomicAdd(&scores[m0 + 0], rs[0]);
            atomicAdd(&scores[m0 + 1], rs[1]);
            atomicAdd(&scores[m0 + 2], rs[2]);
            atomicAdd(&scores[m0 + 3], rs[3]);
        }
    }
}

// ---------- K3: fused softmax + context (reads bf16 encB, direct stores) ----

__global__ __launch_bounds__(512) void k_ctx(const ushort_t* __restrict__ encB,
                                             const float* __restrict__ scores,
                                             float* __restrict__ out) {
    const int b = blockIdx.x, ec = blockIdx.y;   // (32, 8)
    const int t = threadIdx.x;
    const int l = t & 31, g = t >> 5;            // g: 0..15 s-phase
    const int lane = t & 63, wv = t >> 6;        // 8 waves
    __shared__ float al[2048];
    __shared__ float red[8];
    __shared__ f32x4 part[16][33];

    // softmax over scores[b, 0..2047]; each thread owns 4 consecutive values
    float4 v = ((const float4*)scores)[b * 512 + t];
    float mx = fmaxf(fmaxf(v.x, v.y), fmaxf(v.z, v.w));
#pragma unroll
    for (int o = 1; o < 64; o <<= 1) mx = fmaxf(mx, __shfl_xor(mx, o, 64));
    if (lane == 0) red[wv] = mx;
    __syncthreads();
    mx = red[0];
#pragma unroll
    for (int j = 1; j < 8; ++j) mx = fmaxf(mx, red[j]);
    float e0 = __expf(v.x - mx), e1 = __expf(v.y - mx);
    float e2 = __expf(v.z - mx), e3 = __expf(v.w - mx);
    float s = e0 + e1 + e2 + e3;
#pragma unroll
    for (int o = 1; o < 64; o <<= 1) s += __shfl_xor(s, o, 64);
    __syncthreads();
    if (lane == 0) red[wv] = s;
    __syncthreads();
    s = 0.f;
#pragma unroll
    for (int j = 0; j < 8; ++j) s += red[j];
    float inv = 1.0f / s;
    float4 a4 = (float4){e0 * inv, e1 * inv, e2 * inv, e3 * inv};
    ((float4*)al)[t] = a4;
    if (ec == 0) ((float4*)(out + 32768 + (size_t)b * 2048))[t] = a4;
    __syncthreads();

    // context[b, ec*128 .. +128) = sum_s alpha[s] * encB[b, s, :]
    const ushort_t* ep = encB + ((size_t)b * 2048 + g) * 1024 + ec * 128 + l * 4;
    f32x4 acc = (f32x4){0.f, 0.f, 0.f, 0.f};
#pragma unroll 8
    for (int it = 0; it < 128; ++it) {           // s = g + it*16
        ushort4 ev = *(const ushort4*)(ep + (size_t)it * 16384);
        float a = al[g + it * 16];
        acc.x += a * bf2f(ev.x);
        acc.y += a * bf2f(ev.y);
        acc.z += a * bf2f(ev.z);
        acc.w += a * bf2f(ev.w);
    }
    part[g][l] = acc;
    __syncthreads();
    if (t < 32) {
        f32x4 ss = part[0][t];
#pragma unroll
        for (int gg = 1; gg < 16; ++gg) {
            f32x4 pp = part[gg][t];
            ss.x += pp.x; ss.y += pp.y; ss.z += pp.z; ss.w += pp.w;
        }
        *(float4*)(out + (size_t)b * 1024 + ec * 128 + t * 4) =
            (float4){ss.x, ss.y, ss.z, ss.w};
    }
}

// ---------- launch ----------

extern "C" void kernel_launch(void* const* d_in, const int* in_sizes, int n_in,
                              void* d_out, int out_size, void* d_ws, size_t ws_size,
                              hipStream_t stream) {
    const float* enc  = (const float*)d_in[0];
    const float* dh   = (const float*)d_in[1];
    const float* Wenc = (const float*)d_in[2];
    const float* benc = (const float*)d_in[3];
    const float* Wdec = (const float*)d_in[4];
    const float* bdec = (const float*)d_in[5];
    const float* Wv   = (const float*)d_in[6];
    // b_v is a constant shift on scores -> softmax-invariant, ignored.
    float* out = (float*)d_out;                 // [32*1024 context | 32*2048 alpha]

    char* ws = (char*)d_ws;
    ushort_t* encB  = (ushort_t*)ws;                              // 128 MiB
    ushort_t* wencB = (ushort_t*)(ws + 134217728ull);             // 2 MiB
    float* dproj    = (float*)(ws + 134217728ull + 2097152ull);   // 128 KiB
    float* scores   = (float*)(ws + 134217728ull + 2097152ull + 131072ull); // 256 KiB

    k_front<<<16384, 256, 0, stream>>>(enc, Wenc, dh, Wdec, bdec, benc,
                                       encB, wencB, dproj, (float4*)scores);
    k_gemm_scores<<<4096, 256, 0, stream>>>(encB, wencB, dproj, Wv, scores);
    k_ctx<<<dim3(32, 8), 512, 0, stream>>>(encB, scores, out);
}

// Round 9
// 543.093 us; speedup vs baseline: 1.2683x; 1.2683x over previous
//
#include <hip/hip_runtime.h>

typedef unsigned short ushort_t;
typedef __attribute__((ext_vector_type(8))) short short8;
typedef __attribute__((ext_vector_type(4))) float f32x4;

// ---------- helpers ----------

__device__ __forceinline__ ushort_t f2bf(float f) {
    unsigned u = __builtin_bit_cast(unsigned, f);
    u += 0x7fffu + ((u >> 16) & 1u);   // round-to-nearest-even
    return (ushort_t)(u >> 16);
}

__device__ __forceinline__ float bf2f(ushort_t h) {
    unsigned u = ((unsigned)h) << 16;
    return __builtin_bit_cast(float, u);
}

__device__ __forceinline__ float tanh_fast(float x) {
    float e = __expf(2.0f * x);
    float r = __builtin_amdgcn_rcpf(e + 1.0f);
    return __builtin_fmaf(-2.0f, r, 1.0f);
}

__device__ __forceinline__ void gld16(const ushort_t* g, ushort_t* lds) {
    __builtin_amdgcn_global_load_lds(
        (const __attribute__((address_space(1))) unsigned int*)g,
        (__attribute__((address_space(3))) unsigned int*)lds, 16, 0, 0);
}

// ---------- K_front: enc/Wenc fp32->bf16 + zero scores (blocks 0..8191)
//                     dproj = dh@Wdec^T + bdec + benc      (blocks 8192..16383)

__global__ __launch_bounds__(256) void k_front(const float* __restrict__ enc,
                                               const float* __restrict__ Wenc,
                                               const float* __restrict__ dh,
                                               const float* __restrict__ Wd,
                                               const float* __restrict__ bd,
                                               const float* __restrict__ be,
                                               ushort_t* __restrict__ encB,
                                               ushort_t* __restrict__ wencB,
                                               float* __restrict__ dproj,
                                               float4* __restrict__ scores4) {
    const int bx = blockIdx.x;
    const int t = threadIdx.x;
    if (bx < 8192) {
        int i = bx * 256 + t;
        for (; i < 17055744; i += 2097152) {
            if (i < 16777216) {                       // enc: 16.7M float4
                float4 v = ((const float4*)enc)[i];
                ushort4 o;
                o.x = f2bf(v.x); o.y = f2bf(v.y); o.z = f2bf(v.z); o.w = f2bf(v.w);
                ((ushort4*)encB)[i] = o;
            } else if (i < 17039360) {                // Wenc: 262144 float4
                int j = i - 16777216;
                float4 v = ((const float4*)Wenc)[j];
                ushort4 o;
                o.x = f2bf(v.x); o.y = f2bf(v.y); o.z = f2bf(v.z); o.w = f2bf(v.w);
                ((ushort4*)wencB)[j] = o;
            } else {                                  // scores zeros
                scores4[i - 17039360] = (float4){0.f, 0.f, 0.f, 0.f};
            }
        }
    } else {
        int wid = (bx - 8192) * 4 + (t >> 6);
        int lane = t & 63;
        int a = wid & 1023, b = wid >> 10;
        const float4* x = (const float4*)(dh + (size_t)b * 1024);
        const float4* wrow = (const float4*)(Wd + (size_t)a * 1024);
        float s = 0.f;
#pragma unroll
        for (int it = 0; it < 4; ++it) {
            int c = it * 64 + lane;
            float4 xv = x[c], wv = wrow[c];
            s += xv.x * wv.x + xv.y * wv.y + xv.z * wv.z + xv.w * wv.w;
        }
#pragma unroll
        for (int o = 1; o < 64; o <<= 1) s += __shfl_xor(s, o, 64);
        if (lane == 0) dproj[b * 1024 + a] = s + bd[a] + be[a];
    }
}

// ---------- K2: fused GEMM + tanh + W_v reduction -> scores ----------
// Round-7 structure (measured 158 us, 870 TF, MfmaUtil 38%): simple 2-barrier
// loop, global_load_lds, XOR swizzle, 128x128 tile, 4 waves 2x2, wave tile
// 64x64, BK=64, 32 KB LDS, 3 blocks/CU.
// Residency note (round 8): 3 blocks/CU is the HARD cap -- 4+ forces VGPR<=64
// but acc[4][4] alone is 64 VGPR -> accumulator spill to scratch (measured:
// VGPR 48, WRITE_SIZE 16->375 MB, dur 158->298 us). Do not raise.

__global__ __launch_bounds__(256, 3) void k_gemm_scores(const ushort_t* __restrict__ A,
                                                        const ushort_t* __restrict__ Bm,
                                                        const float* __restrict__ dproj,
                                                        const float* __restrict__ Wv,
                                                        float* __restrict__ scores) {
    __shared__ __align__(16) ushort_t At[128 * 64];  // 16 KB
    __shared__ __align__(16) ushort_t Bt[128 * 64];  // 16 KB

    const int tid = threadIdx.x;
    const int lane = tid & 63;
    const int w = tid >> 6;            // wave 0..3
    const int wm = w >> 1, wn = w & 1; // waves: 2 (M) x 2 (N); wave tile 64x64

    // bijective XCD map (4096 % 8 == 0): the 8 N-sharers of an A-panel are
    // consecutive work-units on one XCD -> A-panel L2 locality.
    const int blk = blockIdx.x;        // 0..4095
    const int xcd = blk & 7;
    const int idx = blk >> 3;          // 0..511
    const int blkN = idx & 7;          // 0..7
    const int blkM = xcd + ((idx >> 3) << 3);  // 0..511
    const long long arow0 = (long long)blkM * 128;
    const int brow0 = blkN * 128;

    const int sr = lane >> 3;          // row within 8-row staging group
    const int sgrp = lane & 7;         // 16B slot within row
    const int c8s = sgrp ^ sr;         // XOR-swizzled source column-group

    const int q = lane >> 4;           // quad
    const int ml = lane & 15;

    // wave w stages rows [w*32, w*32+32) of each 128-row panel (4 passes of 8)
    const ushort_t* ga = A + (arow0 + w * 32 + sr) * 1024 + c8s * 8;
    const ushort_t* gb = Bm + (long long)(brow0 + w * 32 + sr) * 1024 + c8s * 8;

    f32x4 acc[4][4];
#pragma unroll
    for (int i = 0; i < 4; ++i)
#pragma unroll
        for (int jj = 0; jj < 4; ++jj) acc[i][jj] = (f32x4){0.f, 0.f, 0.f, 0.f};

    for (int k0 = 0; k0 < 1024; k0 += 64) {
        __syncthreads();   // previous compute done before overwriting LDS
#pragma unroll
        for (int j = 0; j < 4; ++j)                   // A: 32 rows per wave
            gld16(ga + j * 8192, &At[(w * 4 + j) * 512]);
#pragma unroll
        for (int j = 0; j < 4; ++j)                   // B: 32 rows per wave
            gld16(gb + j * 8192, &Bt[(w * 4 + j) * 512]);
        ga += 64; gb += 64;
        __builtin_amdgcn_s_waitcnt(0);  // drain vmcnt before barrier
        __syncthreads();

#pragma unroll
        for (int kk = 0; kk < 2; ++kk) {  // two k-steps of 32
            const int kb = kk * 4;
            const int slot = (kb + q) ^ (ml & 7);     // same for A and B frags
            short8 af[4], bfr[4];
#pragma unroll
            for (int i = 0; i < 4; ++i) {
                int row = wm * 64 + i * 16 + ml;
                af[i] = *(const short8*)&At[row * 64 + slot * 8];
            }
#pragma unroll
            for (int jj = 0; jj < 4; ++jj) {
                int col = wn * 64 + jj * 16 + ml;
                bfr[jj] = *(const short8*)&Bt[col * 64 + slot * 8];
            }
#pragma unroll
            for (int i = 0; i < 4; ++i)
#pragma unroll
                for (int jj = 0; jj < 4; ++jj)
                    acc[i][jj] = __builtin_amdgcn_mfma_f32_16x16x32_bf16(
                        af[i], bfr[jj], acc[i][jj], 0, 0, 0);
        }
    }

    // epilogue: scores[m] += sum_a Wv[a]*tanh(acc + dproj[b,a]) over 128 cols
    const int bb = blkM >> 4;  // 16 M-blocks (128 rows) per batch (2048 rows)
    float dp[4], wv[4];
#pragma unroll
    for (int jj = 0; jj < 4; ++jj) {
        int a = blkN * 128 + wn * 64 + jj * 16 + ml;
        dp[jj] = dproj[bb * 1024 + a];
        wv[jj] = Wv[a];
    }
#pragma unroll
    for (int i = 0; i < 4; ++i) {
        float rs[4] = {0.f, 0.f, 0.f, 0.f};
#pragma unroll
        for (int jj = 0; jj < 4; ++jj) {
            f32x4 v = acc[i][jj];
            rs[0] += wv[jj] * tanh_fast(v.x + dp[jj]);
            rs[1] += wv[jj] * tanh_fast(v.y + dp[jj]);
            rs[2] += wv[jj] * tanh_fast(v.z + dp[jj]);
            rs[3] += wv[jj] * tanh_fast(v.w + dp[jj]);
        }
#pragma unroll
        for (int r = 0; r < 4; ++r)
#pragma unroll
            for (int o = 1; o < 16; o <<= 1) rs[r] += __shfl_xor(rs[r], o, 64);
        if (ml == 0) {
            long long m0 = arow0 + wm * 64 + i * 16 + q * 4;
            atomicAdd(&scores[m0 + 0], rs[0]);
            atomicAdd(&scores[m0 + 1], rs[1]);
            atomicAdd(&scores[m0 + 2], rs[2]);
            atomicAdd(&scores[m0 + 3], rs[3]);
        }
    }
}

// ---------- K3: fused softmax + context (reads bf16 encB, direct stores) ----

__global__ __launch_bounds__(512) void k_ctx(const ushort_t* __restrict__ encB,
                                             const float* __restrict__ scores,
                                             float* __restrict__ out) {
    const int b = blockIdx.x, ec = blockIdx.y;   // (32, 8)
    const int t = threadIdx.x;
    const int l = t & 31, g = t >> 5;            // g: 0..15 s-phase
    const int lane = t & 63, wv = t >> 6;        // 8 waves
    __shared__ float al[2048];
    __shared__ float red[8];
    __shared__ f32x4 part[16][33];

    // softmax over scores[b, 0..2047]; each thread owns 4 consecutive values
    float4 v = ((const float4*)scores)[b * 512 + t];
    float mx = fmaxf(fmaxf(v.x, v.y), fmaxf(v.z, v.w));
#pragma unroll
    for (int o = 1; o < 64; o <<= 1) mx = fmaxf(mx, __shfl_xor(mx, o, 64));
    if (lane == 0) red[wv] = mx;
    __syncthreads();
    mx = red[0];
#pragma unroll
    for (int j = 1; j < 8; ++j) mx = fmaxf(mx, red[j]);
    float e0 = __expf(v.x - mx), e1 = __expf(v.y - mx);
    float e2 = __expf(v.z - mx), e3 = __expf(v.w - mx);
    float s = e0 + e1 + e2 + e3;
#pragma unroll
    for (int o = 1; o < 64; o <<= 1) s += __shfl_xor(s, o, 64);
    __syncthreads();
    if (lane == 0) red[wv] = s;
    __syncthreads();
    s = 0.f;
#pragma unroll
    for (int j = 0; j < 8; ++j) s += red[j];
    float inv = 1.0f / s;
    float4 a4 = (float4){e0 * inv, e1 * inv, e2 * inv, e3 * inv};
    ((float4*)al)[t] = a4;
    if (ec == 0) ((float4*)(out + 32768 + (size_t)b * 2048))[t] = a4;
    __syncthreads();

    // context[b, ec*128 .. +128) = sum_s alpha[s] * encB[b, s, :]
    const ushort_t* ep = encB + ((size_t)b * 2048 + g) * 1024 + ec * 128 + l * 4;
    f32x4 acc = (f32x4){0.f, 0.f, 0.f, 0.f};
#pragma unroll 8
    for (int it = 0; it < 128; ++it) {           // s = g + it*16
        ushort4 ev = *(const ushort4*)(ep + (size_t)it * 16384);
        float a = al[g + it * 16];
        acc.x += a * bf2f(ev.x);
        acc.y += a * bf2f(ev.y);
        acc.z += a * bf2f(ev.z);
        acc.w += a * bf2f(ev.w);
    }
    part[g][l] = acc;
    __syncthreads();
    if (t < 32) {
        f32x4 ss = part[0][t];
#pragma unroll
        for (int gg = 1; gg < 16; ++gg) {
            f32x4 pp = part[gg][t];
            ss.x += pp.x; ss.y += pp.y; ss.z += pp.z; ss.w += pp.w;
        }
        *(float4*)(out + (size_t)b * 1024 + ec * 128 + t * 4) =
            (float4){ss.x, ss.y, ss.z, ss.w};
    }
}

// ---------- launch ----------

extern "C" void kernel_launch(void* const* d_in, const int* in_sizes, int n_in,
                              void* d_out, int out_size, void* d_ws, size_t ws_size,
                              hipStream_t stream) {
    const float* enc  = (const float*)d_in[0];
    const float* dh   = (const float*)d_in[1];
    const float* Wenc = (const float*)d_in[2];
    const float* benc = (const float*)d_in[3];
    const float* Wdec = (const float*)d_in[4];
    const float* bdec = (const float*)d_in[5];
    const float* Wv   = (const float*)d_in[6];
    // b_v is a constant shift on scores -> softmax-invariant, ignored.
    float* out = (float*)d_out;                 // [32*1024 context | 32*2048 alpha]

    char* ws = (char*)d_ws;
    ushort_t* encB  = (ushort_t*)ws;                              // 128 MiB
    ushort_t* wencB = (ushort_t*)(ws + 134217728ull);             // 2 MiB
    float* dproj    = (float*)(ws + 134217728ull + 2097152ull);   // 128 KiB
    float* scores   = (float*)(ws + 134217728ull + 2097152ull + 131072ull); // 256 KiB

    k_front<<<16384, 256, 0, stream>>>(enc, Wenc, dh, Wdec, bdec, benc,
                                       encB, wencB, dproj, (float4*)scores);
    k_gemm_scores<<<4096, 256, 0, stream>>>(encB, wencB, dproj, Wv, scores);
    k_ctx<<<dim3(32, 8), 512, 0, stream>>>(encB, scores, out);
}